// Round 24
// baseline (1075.133 us; speedup 1.0000x reference)
//
#include <hip/hip_runtime.h>
#include <hip/hip_bf16.h>
#include <stdint.h>

#define S_LEN 4096
#define HN    32
#define SSD   64
#define KD    2048      // D_IN = H*SS = D_OUT
#define MROWS 16384     // B*S

typedef __attribute__((ext_vector_type(4))) float f32x4;
typedef __attribute__((ext_vector_type(8))) short bf16x8;
typedef __attribute__((ext_vector_type(2))) int i32x2;
typedef __attribute__((ext_vector_type(4))) int i32x4;
typedef __attribute__((ext_vector_type(2))) _Float16 f16x2;
typedef __attribute__((address_space(3))) char as3char;
typedef __attribute__((address_space(1))) char as1char;

__device__ __forceinline__ unsigned short f2bf(float f){
  unsigned int u = __float_as_uint(f);
  u += 0x7FFFu + ((u >> 16) & 1u);   // round-to-nearest-even
  return (unsigned short)(u >> 16);
}
__device__ __forceinline__ float bf2f_u(unsigned u){     // low 16 bits = bf16
  return __uint_as_float(u << 16);
}
__device__ __forceinline__ f16x2 bc_h2(int v){
  union { int i; f16x2 h; } u; u.i = v; return u.h;
}

// ---------------- convert f32 -> bf16 (vectorized, 4 elts/thread) ----------------
__global__ __launch_bounds__(256) void cvt_bf16_k(const float* __restrict__ src,
                                                  unsigned short* __restrict__ dst){
  int i = (blockIdx.x * 256 + threadIdx.x) * 4;
  float4 v = *(const float4*)(src + i);
  ushort4 r;
  r.x = f2bf(v.x); r.y = f2bf(v.y); r.z = f2bf(v.z); r.w = f2bf(v.w);
  *(ushort4*)(dst + i) = r;
}

// ------- GEMM (bf16, global_load_lds, 2-stage dbuf with COUNTED vmcnt) -------
// R23 race root-cause (rule #18): bare s_barrier let the compiler sink
// MFMAs + their lgkmcnt waits below bar2, so a wave could pass bar2 with
// ds_reads of buf[x] in flight while other waves staged into LDS -> absmax
// 0.26. Fix: bar2 = s_waitcnt lgkmcnt(0) + s_barrier (wave drains its DS
// queue before the barrier). bar1 keeps the COUNTED vmcnt(4): next-tile
// loads stay in flight across the barrier (T4, m218).
template <bool BF16OUT>
__global__ __launch_bounds__(256) void gemm_bf16_k(const unsigned short* __restrict__ A,
                                                   const unsigned short* __restrict__ Bw,
                                                   const float* __restrict__ bias,  // may be null
                                                   void* __restrict__ Cv){
  __shared__ short As[2][128*32];
  __shared__ short Bs[2][128*32];
  const int tid  = threadIdx.x;
  const int bn   = blockIdx.x & 15;
  const int bm   = blockIdx.x >> 4;
  const int lane = tid & 63;
  const int wv   = tid >> 6;
  const int wvU  = __builtin_amdgcn_readfirstlane(wv);
  const int wm   = (wv >> 1) * 64;
  const int wn   = (wv & 1) * 64;

  f32x4 acc[4][4];
#pragma unroll
  for (int i=0;i<4;i++)
#pragma unroll
    for (int j=0;j<4;j++)
#pragma unroll
      for (int q=0;q<4;q++) acc[i][j][q] = 0.0f;

  as1char* aG  = (as1char*)A;
  as1char* bG  = (as1char*)Bw;

  const int fr  = lane & 15;
  const int fko = (lane >> 4) * 8;

  // stage one 128x32 A-tile + B-tile of K-step `kt` into buffer `bf` (4 loads)
#define STAGE(bf, kt) { \
    _Pragma("unroll") \
    for (int c=0;c<2;c++){ \
      const int off  = (wvU*2 + c)*1024 + lane*16; \
      const int row  = off >> 6; \
      const int colB = off & 63; \
      __builtin_amdgcn_global_load_lds( \
        (__attribute__((address_space(1))) void*)(aG + (size_t)(bm*128 + row)*4096 + (size_t)(kt)*64 + colB), \
        (__attribute__((address_space(3))) void*)((as3char*)As + (size_t)(bf)*8192 + (wvU*2 + c)*1024), \
        16, 0, 0); \
      __builtin_amdgcn_global_load_lds( \
        (__attribute__((address_space(1))) void*)(bG + (size_t)(bn*128 + row)*4096 + (size_t)(kt)*64 + colB), \
        (__attribute__((address_space(3))) void*)((as3char*)Bs + (size_t)(bf)*8192 + (wvU*2 + c)*1024), \
        16, 0, 0); \
    } }

  STAGE(0, 0)                          // prologue: 4 loads outstanding

  int cur = 0;
  for (int kt = 0; kt < KD/32; ++kt){
    if (kt + 1 < KD/32){
      STAGE(cur^1, kt+1)               // +4 loads (8 outstanding)
      asm volatile("s_waitcnt vmcnt(4)" ::: "memory");  // oldest 4 (buf[cur]) landed
    } else {
      asm volatile("s_waitcnt vmcnt(0)" ::: "memory");  // last tile: drain
    }
    asm volatile("s_barrier" ::: "memory");             // all waves' loads landed
    __builtin_amdgcn_sched_barrier(0);                  // pin: nothing hoists above

    const short* as = &As[cur][0];
    const short* bs = &Bs[cur][0];
    bf16x8 af[4], bq[4];
#pragma unroll
    for (int mt=0; mt<4; mt++) af[mt] = *(const bf16x8*)&as[(wm + mt*16 + fr)*32 + fko];
#pragma unroll
    for (int nt=0; nt<4; nt++) bq[nt] = *(const bf16x8*)&bs[(wn + nt*16 + fr)*32 + fko];
#pragma unroll
    for (int mt=0; mt<4; mt++)
#pragma unroll
      for (int nt=0; nt<4; nt++)
        acc[mt][nt] = __builtin_amdgcn_mfma_f32_16x16x32_bf16(af[mt], bq[nt], acc[mt][nt], 0, 0, 0);

    // bar2: drain OWN ds_reads before passing (closes rule-#18 sink race),
    // then barrier so no wave stages into a buffer still being read.
    asm volatile("s_waitcnt lgkmcnt(0)\n\ts_barrier" ::: "memory");
    cur ^= 1;
  }
#undef STAGE

  float bv[4] = {0.f, 0.f, 0.f, 0.f};
  if (bias){
#pragma unroll
    for (int nt=0; nt<4; nt++) bv[nt] = bias[bn*128 + wn + nt*16 + fr];
  }
#pragma unroll
  for (int mt=0; mt<4; mt++)
#pragma unroll
    for (int nt=0; nt<4; nt++){
      const int col = bn*128 + wn + nt*16 + fr;
#pragma unroll
      for (int q=0; q<4; q++){
        const int row = bm*128 + wm + mt*16 + (lane>>4)*4 + q;
        const float v = acc[mt][nt][q] + bv[nt];
        if constexpr (BF16OUT) ((unsigned short*)Cv)[(size_t)row*KD + col] = f2bf(v);
        else                   ((float*)Cv)[(size_t)row*KD + col] = v;
      }
    }
}

// ---------------- scan: y_t = tanh(W_h y_{t-1} + hx_t) ----------------
// R22-proven (692us): ONE wave per (b,h) chain; LDS uniform-address b128
// broadcast (f16 pairs) + 32 v_dot2; 32 asm-pinned named f16x2 weights;
// 4-deep RAW-ushort hx prefetch (bf16, convert at consumption); 4-step
// store staging. Established latency floor ~406 cyc/step.
__global__ __attribute__((amdgpu_flat_work_group_size(64, 64)))
__attribute__((amdgpu_waves_per_eu(1, 1)))
void scan_k(const unsigned short* __restrict__ hx,  // [MROWS][2048] bf16
            const float* __restrict__ sw,   // [32][64][64]
            const float* __restrict__ st0,  // [4][32][64]
            unsigned short* __restrict__ ybf){ // [MROWS][2048] bf16
  const int b = blockIdx.x >> 5, h = blockIdx.x & 31;
  const int lane = threadIdx.x;        // = output index o
  const f32x4* wv = (const f32x4*)(sw + ((size_t)(h*64 + lane))*64);

  // pack W row into 32 named f16x2 (pairs (2k,2k+1))
#define MKP(Q, PA, PB) { f32x4 q_ = wv[Q]; \
    PA = f16x2{(_Float16)q_[0], (_Float16)q_[1]}; \
    PB = f16x2{(_Float16)q_[2], (_Float16)q_[3]}; }
  f16x2 p0,p1,p2,p3,p4,p5,p6,p7,p8,p9,p10,p11,p12,p13,p14,p15,
        p16,p17,p18,p19,p20,p21,p22,p23,p24,p25,p26,p27,p28,p29,p30,p31;
  MKP(0,p0,p1)   MKP(1,p2,p3)   MKP(2,p4,p5)   MKP(3,p6,p7)
  MKP(4,p8,p9)   MKP(5,p10,p11) MKP(6,p12,p13) MKP(7,p14,p15)
  MKP(8,p16,p17) MKP(9,p18,p19) MKP(10,p20,p21)MKP(11,p22,p23)
  MKP(12,p24,p25)MKP(13,p26,p27)MKP(14,p28,p29)MKP(15,p30,p31)
#undef MKP
  asm volatile("" : "+v"(p0),"+v"(p1),"+v"(p2),"+v"(p3),"+v"(p4),"+v"(p5),
                    "+v"(p6),"+v"(p7),"+v"(p8),"+v"(p9),"+v"(p10),"+v"(p11),
                    "+v"(p12),"+v"(p13),"+v"(p14),"+v"(p15));
  asm volatile("" : "+v"(p16),"+v"(p17),"+v"(p18),"+v"(p19),"+v"(p20),"+v"(p21),
                    "+v"(p22),"+v"(p23),"+v"(p24),"+v"(p25),"+v"(p26),"+v"(p27),
                    "+v"(p28),"+v"(p29),"+v"(p30),"+v"(p31));

  __shared__ __align__(16) unsigned short yf16[2][64];   // f16 recurrence buffer
  __shared__ __align__(16) unsigned short ybuf[4][64];   // bf16 global staging

  float y = st0[(b*32 + h)*64 + lane];
  yf16[0][lane] = (unsigned short)__builtin_bit_cast(unsigned short, (_Float16)y);

  const unsigned short* hxp = hx + (size_t)b*S_LEN*KD + h*64 + lane;
  unsigned short* const ybase = ybf + (size_t)b*S_LEN*KD + h*64;  // chain base
  const int srow = lane >> 4;          // drain: buffered row (0..3)
  const int scol = (lane & 15) << 2;   // drain: 4-ushort (8B) chunk in row

  // named RAW-ushort prefetch registers (pure loads; convert at consumption)
  unsigned h0 = hxp[0*(size_t)KD], h1 = hxp[1*(size_t)KD],
           h2 = hxp[2*(size_t)KD], h3 = hxp[3*(size_t)KD];

// 4 dot2 from one i32x4 broadcast (pairs 4k..4k+3)
#define DOT4(R, PA,PB,PC,PD) \
    a0 = __builtin_amdgcn_fdot2(PA, bc_h2(R[0]), a0, false); \
    a1 = __builtin_amdgcn_fdot2(PB, bc_h2(R[1]), a1, false); \
    a2 = __builtin_amdgcn_fdot2(PC, bc_h2(R[2]), a2, false); \
    a3 = __builtin_amdgcn_fdot2(PD, bc_h2(R[3]), a3, false);

#define RNN_STEP(H, J, TT, CUR, NXT) { \
    const float hxv = bf2f_u(H);          /* convert at consumption */ \
    { const int tn_ = ((TT) + 4 < S_LEN) ? ((TT) + 4) : (S_LEN - 1); \
      H = hxp[(size_t)tn_ * KD]; }        /* pure load, no dependent op */ \
    const i32x4* yb4 = (const i32x4*)yf16[CUR];   /* wave-uniform addr */ \
    const i32x4 r0 = yb4[0], r1 = yb4[1], r2 = yb4[2], r3 = yb4[3]; \
    const i32x4 r4 = yb4[4], r5 = yb4[5], r6 = yb4[6], r7 = yb4[7]; \
    float a0=0.f, a1=0.f, a2=0.f, a3=0.f; \
    DOT4(r0, p0,p1,p2,p3)     DOT4(r1, p4,p5,p6,p7) \
    DOT4(r2, p8,p9,p10,p11)   DOT4(r3, p12,p13,p14,p15) \
    DOT4(r4, p16,p17,p18,p19) DOT4(r5, p20,p21,p22,p23) \
    DOT4(r6, p24,p25,p26,p27) DOT4(r7, p28,p29,p30,p31) \
    const float u = (a0 + a1) + (a2 + a3) + hxv; \
    const float e = __expf(2.0f*u); \
    y = 1.0f - 2.0f*__builtin_amdgcn_rcpf(e + 1.0f); \
    yf16[NXT][lane] = (unsigned short)__builtin_bit_cast(unsigned short, (_Float16)y); \
    ybuf[J][lane] = f2bf(y); }

  for (int t = 0; t < S_LEN; t += 4){
    RNN_STEP(h0, 0, t+0, 0, 1)
    RNN_STEP(h1, 1, t+1, 1, 0)
    RNN_STEP(h2, 2, t+2, 0, 1)
    RNN_STEP(h3, 3, t+3, 1, 0)
    // drain the 4-step tile: one 8B store per lane (rows t..t+3)
    const i32x2 v = *(const i32x2*)&ybuf[srow][scol];
    *(i32x2*)(ybase + (size_t)(t + srow)*KD + scol) = v;
  }
#undef RNN_STEP
#undef DOT4
}

extern "C" void kernel_launch(void* const* d_in, const int* in_sizes, int n_in,
                              void* d_out, int out_size, void* d_ws, size_t ws_size,
                              hipStream_t stream) {
  const float* x      = (const float*)d_in[0];
  const float* st0    = (const float*)d_in[1];
  const float* w_in   = (const float*)d_in[2];
  const float* w_st   = (const float*)d_in[3];
  const float* b_st   = (const float*)d_in[4];
  const float* w_out  = (const float*)d_in[5];
  float* out = (float*)d_out;

  // workspace: hx bf16 (67MB) | y/x bf16 (67MB) | w bf16 (8MB) = 142 MiB
  const size_t HX_B = (size_t)MROWS * KD * 2;       // 67108864 (bf16)
  const size_t Y_B  = (size_t)MROWS * KD * 2;       // 67108864
  const size_t WO_B = (size_t)KD * KD * 2;          // 8388608
  if (ws_size < HX_B + Y_B + WO_B) return;          // fail loudly rather than corrupt
  char* ws = (char*)d_ws;
  unsigned short* hxbf = (unsigned short*)ws;
  unsigned short* ybf  = (unsigned short*)(ws + HX_B);       // doubles as x_bf16
  unsigned short* wbf  = (unsigned short*)(ws + HX_B + Y_B); // w_in then w_out

  // phase 1: convert x and w_in, input GEMM (+bias) -> hx bf16
  cvt_bf16_k<<<dim3((MROWS*(size_t)KD)/1024), dim3(256), 0, stream>>>(x, ybf);
  cvt_bf16_k<<<dim3((KD*KD)/1024), dim3(256), 0, stream>>>(w_in, wbf);
  gemm_bf16_k<true><<<dim3((MROWS/128)*(KD/128)), dim3(256), 0, stream>>>(ybf, wbf, b_st, hxbf);
  // phase 2: scan (overwrites x_bf16 region with y), then output GEMM
  scan_k<<<dim3(128), dim3(64), 0, stream>>>(hxbf, w_st, st0, ybf);
  cvt_bf16_k<<<dim3((KD*KD)/1024), dim3(256), 0, stream>>>(w_out, wbf);
  gemm_bf16_k<false><<<dim3((MROWS/128)*(KD/128)), dim3(256), 0, stream>>>(ybf, wbf, nullptr, out);
}

// Round 25
// 1046.201 us; speedup vs baseline: 1.0277x; 1.0277x over previous
//
#include <hip/hip_runtime.h>
#include <hip/hip_bf16.h>
#include <stdint.h>

#define S_LEN 4096
#define HN    32
#define SSD   64
#define KD    2048      // D_IN = H*SS = D_OUT
#define MROWS 16384     // B*S

typedef __attribute__((ext_vector_type(4))) float f32x4;
typedef __attribute__((ext_vector_type(8))) short bf16x8;
typedef __attribute__((ext_vector_type(2))) int i32x2;
typedef __attribute__((ext_vector_type(4))) int i32x4;
typedef __attribute__((ext_vector_type(2))) _Float16 f16x2;
typedef __attribute__((address_space(3))) char as3char;
typedef __attribute__((address_space(1))) char as1char;

__device__ __forceinline__ unsigned short f2bf(float f){
  unsigned int u = __float_as_uint(f);
  u += 0x7FFFu + ((u >> 16) & 1u);   // round-to-nearest-even
  return (unsigned short)(u >> 16);
}
__device__ __forceinline__ float bf2f_u(unsigned u){     // low 16 bits = bf16
  return __uint_as_float(u << 16);
}
__device__ __forceinline__ f16x2 bc_h2(int v){
  union { int i; f16x2 h; } u; u.i = v; return u.h;
}

// ---------------- convert f32 -> bf16 (vectorized, 4 elts/thread) ----------------
__global__ __launch_bounds__(256) void cvt_bf16_k(const float* __restrict__ src,
                                                  unsigned short* __restrict__ dst){
  int i = (blockIdx.x * 256 + threadIdx.x) * 4;
  float4 v = *(const float4*)(src + i);
  ushort4 r;
  r.x = f2bf(v.x); r.y = f2bf(v.y); r.z = f2bf(v.z); r.w = f2bf(v.w);
  *(ushort4*)(dst + i) = r;
}

// ---------------- GEMM (bf16, global_load_lds) — R22 proven structure ----------------
// Final config: 16KB single-buffer m97-style loop, 8 blocks/CU. Both dbuf
// variants (R16 __syncthreads, R24 counted-vmcnt) lost: the 32KB-LDS
// occupancy tax (8->5 blocks/CU) exceeds the barrier-drain recovery at this
// tile size. BF16OUT: bf16 C-store for hx (halves write traffic).
template <bool BF16OUT>
__global__ __launch_bounds__(256) void gemm_bf16_k(const unsigned short* __restrict__ A,
                                                   const unsigned short* __restrict__ Bw,
                                                   const float* __restrict__ bias,  // may be null
                                                   void* __restrict__ Cv){
  __shared__ short As[128*32];
  __shared__ short Bs[128*32];
  const int tid  = threadIdx.x;
  const int bn   = blockIdx.x & 15;
  const int bm   = blockIdx.x >> 4;
  const int lane = tid & 63;
  const int wv   = tid >> 6;
  const int wvU  = __builtin_amdgcn_readfirstlane(wv);
  const int wm   = (wv >> 1) * 64;
  const int wn   = (wv & 1) * 64;

  f32x4 acc[4][4];
#pragma unroll
  for (int i=0;i<4;i++)
#pragma unroll
    for (int j=0;j<4;j++)
#pragma unroll
      for (int q=0;q<4;q++) acc[i][j][q] = 0.0f;

  as3char* asB = (as3char*)As;
  as3char* bsB = (as3char*)Bs;
  as1char* aG  = (as1char*)A;
  as1char* bG  = (as1char*)Bw;

  const int fr  = lane & 15;
  const int fko = (lane >> 4) * 8;

  for (int kt=0; kt<KD/32; ++kt){
    __syncthreads();                 // previous tile's frag reads done
#pragma unroll
    for (int c=0;c<2;c++){
      const int off  = (wvU*2 + c)*1024 + lane*16;
      const int row  = off >> 6;
      const int colB = off & 63;
      __builtin_amdgcn_global_load_lds(
        (__attribute__((address_space(1))) void*)(aG + (size_t)(bm*128 + row)*4096 + (size_t)kt*64 + colB),
        (__attribute__((address_space(3))) void*)(asB + (wvU*2 + c)*1024),
        16, 0, 0);
      __builtin_amdgcn_global_load_lds(
        (__attribute__((address_space(1))) void*)(bG + (size_t)(bn*128 + row)*4096 + (size_t)kt*64 + colB),
        (__attribute__((address_space(3))) void*)(bsB + (wvU*2 + c)*1024),
        16, 0, 0);
    }
    __syncthreads();                 // loads landed (vmcnt drain at barrier)

    bf16x8 af[4], bq[4];
#pragma unroll
    for (int mt=0; mt<4; mt++) af[mt] = *(const bf16x8*)&As[(wm + mt*16 + fr)*32 + fko];
#pragma unroll
    for (int nt=0; nt<4; nt++) bq[nt] = *(const bf16x8*)&Bs[(wn + nt*16 + fr)*32 + fko];
#pragma unroll
    for (int mt=0; mt<4; mt++)
#pragma unroll
      for (int nt=0; nt<4; nt++)
        acc[mt][nt] = __builtin_amdgcn_mfma_f32_16x16x32_bf16(af[mt], bq[nt], acc[mt][nt], 0, 0, 0);
  }

  float bv[4] = {0.f, 0.f, 0.f, 0.f};
  if (bias){
#pragma unroll
    for (int nt=0; nt<4; nt++) bv[nt] = bias[bn*128 + wn + nt*16 + fr];
  }
#pragma unroll
  for (int mt=0; mt<4; mt++)
#pragma unroll
    for (int nt=0; nt<4; nt++){
      const int col = bn*128 + wn + nt*16 + fr;
#pragma unroll
      for (int q=0; q<4; q++){
        const int row = bm*128 + wm + mt*16 + (lane>>4)*4 + q;
        const float v = acc[mt][nt][q] + bv[nt];
        if constexpr (BF16OUT) ((unsigned short*)Cv)[(size_t)row*KD + col] = f2bf(v);
        else                   ((float*)Cv)[(size_t)row*KD + col] = v;
      }
    }
}

// ---------------- scan: y_t = tanh(W_h y_{t-1} + hx_t) ----------------
// R22-proven (692us, ~406 cyc/step latency floor): ONE wave per (b,h) chain;
// y broadcast via LDS UNIFORM-ADDRESS b128 reads (f16 pairs) feeding 32
// v_dot2_f32_f16; weights in 32 asm-pinned named f16x2 regs; 4-deep
// RAW-ushort hx prefetch (bf16 in memory, convert at consumption); 4-step
// bf16 store staging via LDS.
__global__ __attribute__((amdgpu_flat_work_group_size(64, 64)))
__attribute__((amdgpu_waves_per_eu(1, 1)))
void scan_k(const unsigned short* __restrict__ hx,  // [MROWS][2048] bf16
            const float* __restrict__ sw,   // [32][64][64]
            const float* __restrict__ st0,  // [4][32][64]
            unsigned short* __restrict__ ybf){ // [MROWS][2048] bf16
  const int b = blockIdx.x >> 5, h = blockIdx.x & 31;
  const int lane = threadIdx.x;        // = output index o
  const f32x4* wv = (const f32x4*)(sw + ((size_t)(h*64 + lane))*64);

  // pack W row into 32 named f16x2 (pairs (2k,2k+1))
#define MKP(Q, PA, PB) { f32x4 q_ = wv[Q]; \
    PA = f16x2{(_Float16)q_[0], (_Float16)q_[1]}; \
    PB = f16x2{(_Float16)q_[2], (_Float16)q_[3]}; }
  f16x2 p0,p1,p2,p3,p4,p5,p6,p7,p8,p9,p10,p11,p12,p13,p14,p15,
        p16,p17,p18,p19,p20,p21,p22,p23,p24,p25,p26,p27,p28,p29,p30,p31;
  MKP(0,p0,p1)   MKP(1,p2,p3)   MKP(2,p4,p5)   MKP(3,p6,p7)
  MKP(4,p8,p9)   MKP(5,p10,p11) MKP(6,p12,p13) MKP(7,p14,p15)
  MKP(8,p16,p17) MKP(9,p18,p19) MKP(10,p20,p21)MKP(11,p22,p23)
  MKP(12,p24,p25)MKP(13,p26,p27)MKP(14,p28,p29)MKP(15,p30,p31)
#undef MKP
  asm volatile("" : "+v"(p0),"+v"(p1),"+v"(p2),"+v"(p3),"+v"(p4),"+v"(p5),
                    "+v"(p6),"+v"(p7),"+v"(p8),"+v"(p9),"+v"(p10),"+v"(p11),
                    "+v"(p12),"+v"(p13),"+v"(p14),"+v"(p15));
  asm volatile("" : "+v"(p16),"+v"(p17),"+v"(p18),"+v"(p19),"+v"(p20),"+v"(p21),
                    "+v"(p22),"+v"(p23),"+v"(p24),"+v"(p25),"+v"(p26),"+v"(p27),
                    "+v"(p28),"+v"(p29),"+v"(p30),"+v"(p31));

  __shared__ __align__(16) unsigned short yf16[2][64];   // f16 recurrence buffer
  __shared__ __align__(16) unsigned short ybuf[4][64];   // bf16 global staging

  float y = st0[(b*32 + h)*64 + lane];
  yf16[0][lane] = (unsigned short)__builtin_bit_cast(unsigned short, (_Float16)y);

  const unsigned short* hxp = hx + (size_t)b*S_LEN*KD + h*64 + lane;
  unsigned short* const ybase = ybf + (size_t)b*S_LEN*KD + h*64;  // chain base
  const int srow = lane >> 4;          // drain: buffered row (0..3)
  const int scol = (lane & 15) << 2;   // drain: 4-ushort (8B) chunk in row

  // named RAW-ushort prefetch registers (pure loads; convert at consumption)
  unsigned h0 = hxp[0*(size_t)KD], h1 = hxp[1*(size_t)KD],
           h2 = hxp[2*(size_t)KD], h3 = hxp[3*(size_t)KD];

// 4 dot2 from one i32x4 broadcast (pairs 4k..4k+3)
#define DOT4(R, PA,PB,PC,PD) \
    a0 = __builtin_amdgcn_fdot2(PA, bc_h2(R[0]), a0, false); \
    a1 = __builtin_amdgcn_fdot2(PB, bc_h2(R[1]), a1, false); \
    a2 = __builtin_amdgcn_fdot2(PC, bc_h2(R[2]), a2, false); \
    a3 = __builtin_amdgcn_fdot2(PD, bc_h2(R[3]), a3, false);

#define RNN_STEP(H, J, TT, CUR, NXT) { \
    const float hxv = bf2f_u(H);          /* convert at consumption */ \
    { const int tn_ = ((TT) + 4 < S_LEN) ? ((TT) + 4) : (S_LEN - 1); \
      H = hxp[(size_t)tn_ * KD]; }        /* pure load, no dependent op */ \
    const i32x4* yb4 = (const i32x4*)yf16[CUR];   /* wave-uniform addr */ \
    const i32x4 r0 = yb4[0], r1 = yb4[1], r2 = yb4[2], r3 = yb4[3]; \
    const i32x4 r4 = yb4[4], r5 = yb4[5], r6 = yb4[6], r7 = yb4[7]; \
    float a0=0.f, a1=0.f, a2=0.f, a3=0.f; \
    DOT4(r0, p0,p1,p2,p3)     DOT4(r1, p4,p5,p6,p7) \
    DOT4(r2, p8,p9,p10,p11)   DOT4(r3, p12,p13,p14,p15) \
    DOT4(r4, p16,p17,p18,p19) DOT4(r5, p20,p21,p22,p23) \
    DOT4(r6, p24,p25,p26,p27) DOT4(r7, p28,p29,p30,p31) \
    const float u = (a0 + a1) + (a2 + a3) + hxv; \
    const float e = __expf(2.0f*u); \
    y = 1.0f - 2.0f*__builtin_amdgcn_rcpf(e + 1.0f); \
    yf16[NXT][lane] = (unsigned short)__builtin_bit_cast(unsigned short, (_Float16)y); \
    ybuf[J][lane] = f2bf(y); }

  for (int t = 0; t < S_LEN; t += 4){
    RNN_STEP(h0, 0, t+0, 0, 1)
    RNN_STEP(h1, 1, t+1, 1, 0)
    RNN_STEP(h2, 2, t+2, 0, 1)
    RNN_STEP(h3, 3, t+3, 1, 0)
    // drain the 4-step tile: one 8B store per lane (rows t..t+3)
    const i32x2 v = *(const i32x2*)&ybuf[srow][scol];
    *(i32x2*)(ybase + (size_t)(t + srow)*KD + scol) = v;
  }
#undef RNN_STEP
#undef DOT4
}

extern "C" void kernel_launch(void* const* d_in, const int* in_sizes, int n_in,
                              void* d_out, int out_size, void* d_ws, size_t ws_size,
                              hipStream_t stream) {
  const float* x      = (const float*)d_in[0];
  const float* st0    = (const float*)d_in[1];
  const float* w_in   = (const float*)d_in[2];
  const float* w_st   = (const float*)d_in[3];
  const float* b_st   = (const float*)d_in[4];
  const float* w_out  = (const float*)d_in[5];
  float* out = (float*)d_out;

  // workspace: hx bf16 (67MB) | y/x bf16 (67MB) | w bf16 (8MB) = 142 MiB
  const size_t HX_B = (size_t)MROWS * KD * 2;       // 67108864 (bf16)
  const size_t Y_B  = (size_t)MROWS * KD * 2;       // 67108864
  const size_t WO_B = (size_t)KD * KD * 2;          // 8388608
  if (ws_size < HX_B + Y_B + WO_B) return;          // fail loudly rather than corrupt
  char* ws = (char*)d_ws;
  unsigned short* hxbf = (unsigned short*)ws;
  unsigned short* ybf  = (unsigned short*)(ws + HX_B);       // doubles as x_bf16
  unsigned short* wbf  = (unsigned short*)(ws + HX_B + Y_B); // w_in then w_out

  // phase 1: convert x and w_in, input GEMM (+bias) -> hx bf16
  cvt_bf16_k<<<dim3((MROWS*(size_t)KD)/1024), dim3(256), 0, stream>>>(x, ybf);
  cvt_bf16_k<<<dim3((KD*KD)/1024), dim3(256), 0, stream>>>(w_in, wbf);
  gemm_bf16_k<true><<<dim3((MROWS/128)*(KD/128)), dim3(256), 0, stream>>>(ybf, wbf, b_st, hxbf);
  // phase 2: scan (overwrites x_bf16 region with y), then output GEMM
  scan_k<<<dim3(128), dim3(64), 0, stream>>>(hxbf, w_st, st0, ybf);
  cvt_bf16_k<<<dim3((KD*KD)/1024), dim3(256), 0, stream>>>(w_out, wbf);
  gemm_bf16_k<false><<<dim3((MROWS/128)*(KD/128)), dim3(256), 0, stream>>>(ybf, wbf, nullptr, out);
}